// Round 4
// baseline (12742.907 us; speedup 1.0000x reference)
//
#include <hip/hip_runtime.h>
#include <hip/hip_bf16.h>
#include <stdint.h>

#define B_   64
#define T_   1024
#define I_   512
#define H_   1024
#define TOP_ 256
#define NWG  128
#define NTHR 512
#define PLS  260       // pl row stride (floats)

typedef __bf16 bf16x8 __attribute__((ext_vector_type(8)));
typedef float  f32x4  __attribute__((ext_vector_type(4)));

struct P {
  const float *x, *h0, *c0, *topic, *Wi, *bi, *Wh, *bh, *Wt, *bt;
  float *out, *hN, *cN;
  uint32_t *hb0, *hb1;   // h state, packed bf16 pairs, double-buffered (d_ws)
  uint32_t *flags;       // NWG arrival slots, 64B apart (d_ws)
};

__device__ __forceinline__ bf16x8 cvt8(float4 f0, float4 f1) {
  bf16x8 v;
  v[0]=(__bf16)f0.x; v[1]=(__bf16)f0.y; v[2]=(__bf16)f0.z; v[3]=(__bf16)f0.w;
  v[4]=(__bf16)f1.x; v[5]=(__bf16)f1.y; v[6]=(__bf16)f1.z; v[7]=(__bf16)f1.w;
  return v;
}

__device__ __forceinline__ uint2 pack4(float4 f) {
  uint2 u;
  u.x = (uint32_t)__builtin_bit_cast(uint16_t, (__bf16)f.x)
      | ((uint32_t)__builtin_bit_cast(uint16_t, (__bf16)f.y) << 16);
  u.y = (uint32_t)__builtin_bit_cast(uint16_t, (__bf16)f.z)
      | ((uint32_t)__builtin_bit_cast(uint16_t, (__bf16)f.w) << 16);
  return u;
}

__device__ __forceinline__ float sigm(float x) { return 1.f / (1.f + __expf(-x)); }
__device__ __forceinline__ float tanh_fast(float z) {
  z = fminf(fmaxf(z, -15.f), 15.f);
  float e = __expf(2.f * z);
  return (e - 1.f) / (e + 1.f);
}

__global__ void lstm_init(P p) {
  int i = blockIdx.x * blockDim.x + threadIdx.x;
  if (i < NWG) p.flags[i * 16] = 0;
  if (i < B_ * H_ / 2) {
    float2 f = ((const float2*)p.h0)[i];
    uint16_t lo = __builtin_bit_cast(uint16_t, (__bf16)f.x);
    uint16_t hi = __builtin_bit_cast(uint16_t, (__bf16)f.y);
    p.hb0[i] = (uint32_t)lo | ((uint32_t)hi << 16);
  }
}

__global__ __launch_bounds__(NTHR, 1) void lstm_persist(P p) {
  // xs: x(t) staged in MFMA A-frag layout [kc][m][lane][8 bf16]
  __shared__ ushort xs[16][4][64][8];      // 65536 B
  __shared__ float  pl[B_][PLS];           // 66560 B

  const int wg   = blockIdx.x;
  const int tid  = threadIdx.x;
  const int lane = tid & 63;
  const int w    = tid >> 6;          // wave 0..7
  const int l15  = lane & 15;
  const int hi4  = lane >> 4;         // 0..3
  const int kg8  = hi4 * 8;

  // ---- weights in VGPRs: wave w owns x-chunks {2w,2w+1}, h-chunks {4w..4w+3} ----
  bf16x8 wx[2][2], wh[4][2];
  #pragma unroll
  for (int n = 0; n < 2; ++n) {
    const int row = n * 16 + l15;
    const int R   = (row >> 3) * H_ + wg * 8 + (row & 7);
    #pragma unroll
    for (int i = 0; i < 2; ++i) {
      const float* s = p.Wi + (size_t)R * I_ + (2 * w + i) * 32 + kg8;
      wx[i][n] = cvt8(*(const float4*)s, *(const float4*)(s + 4));
    }
    #pragma unroll
    for (int i = 0; i < 4; ++i) {
      const float* s = p.Wh + (size_t)R * H_ + (4 * w + i) * 32 + kg8;
      wh[i][n] = cvt8(*(const float4*)s, *(const float4*)(s + 4));
    }
  }

  // ---- finish-phase ownership ----
  const int ob = tid >> 3, oc = tid & 7, ocol = wg * 8 + oc;
  float tgv = p.bt[ocol];
  for (int j = 0; j < TOP_ / 4; ++j) {
    float4 tv = ((const float4*)(p.topic + (size_t)ob * TOP_))[j];
    float4 wv = ((const float4*)(p.Wt + (size_t)ocol * TOP_))[j];
    tgv += tv.x * wv.x + tv.y * wv.y + tv.z * wv.z + tv.w * wv.w;
  }
  const float bias_i = p.bi[ocol]        + p.bh[ocol]        + tgv;
  const float bias_f = p.bi[H_ + ocol]   + p.bh[H_ + ocol]   + tgv;
  const float bias_g = p.bi[2*H_ + ocol] + p.bh[2*H_ + ocol];
  const float bias_o = p.bi[3*H_ + ocol] + p.bh[3*H_ + ocol];
  float c = p.c0[ob * H_ + ocol];

  // staging identity: thread (sb,sr) covers x[sb][t][4*(8j+sr)..+3]
  const int sb = tid >> 3, sr = tid & 7;
  const int s_m = sb >> 4, s_lf = (sr >> 1) * 16 + (sb & 15), s_off = (sr & 1) * 4;

  // ---- prologue: xs = x(0); acc = x-part(0); xs = x(1) ----
  #pragma unroll
  for (int j = 0; j < 16; ++j) {
    float4 f = *(const float4*)(p.x + (size_t)sb * T_ * I_ + 4 * (8 * j + sr));
    *(uint2*)&xs[j][s_m][s_lf][s_off] = pack4(f);
  }
  __syncthreads();

  f32x4 acc[4][2];
  #pragma unroll
  for (int m = 0; m < 4; ++m) { acc[m][0] = (f32x4){0,0,0,0}; acc[m][1] = (f32x4){0,0,0,0}; }
  #pragma unroll
  for (int i = 0; i < 2; ++i)
    #pragma unroll
    for (int m = 0; m < 4; ++m) {
      bf16x8 a = *(const bf16x8*)&xs[2 * w + i][m][lane][0];
      acc[m][0] = __builtin_amdgcn_mfma_f32_16x16x32_bf16(a, wx[i][0], acc[m][0], 0, 0, 0);
      acc[m][1] = __builtin_amdgcn_mfma_f32_16x16x32_bf16(a, wx[i][1], acc[m][1], 0, 0, 0);
    }
  {
    float4 xf[16];
    #pragma unroll
    for (int j = 0; j < 16; ++j)
      xf[j] = *(const float4*)(p.x + ((size_t)sb * T_ + 1) * I_ + 4 * (8 * j + sr));
    __syncthreads();
    #pragma unroll
    for (int j = 0; j < 16; ++j)
      *(uint2*)&xs[j][s_m][s_lf][s_off] = pack4(xf[j]);
  }

  for (int t = 0; t < T_; ++t) {
    const __hip_bfloat16* hp = (const __hip_bfloat16*)((t & 1) ? p.hb1 : p.hb0);
    uint32_t*             hn = (t & 1) ? p.hb0 : p.hb1;

    // h(t) loads: 32x 8B agent-scope, issued up front -> one LLC latency round
    bf16x8 hv[4][4];
    #pragma unroll
    for (int i = 0; i < 4; ++i) {
      const int kh = (4 * w + i) * 32 + kg8;
      #pragma unroll
      for (int m = 0; m < 4; ++m) {
        const unsigned long long* q =
            (const unsigned long long*)(hp + (size_t)(m * 16 + l15) * H_ + kh);
        union { bf16x8 v; unsigned long long u[2]; } z;
        z.u[0] = __hip_atomic_load(q,     __ATOMIC_RELAXED, __HIP_MEMORY_SCOPE_AGENT);
        z.u[1] = __hip_atomic_load(q + 1, __ATOMIC_RELAXED, __HIP_MEMORY_SCOPE_AGENT);
        hv[i][m] = z.v;
      }
    }

    // h MFMAs (acc already holds x-part for step t)
    #pragma unroll
    for (int i = 0; i < 4; ++i)
      #pragma unroll
      for (int m = 0; m < 4; ++m) {
        acc[m][0] = __builtin_amdgcn_mfma_f32_16x16x32_bf16(hv[i][m], wh[i][0], acc[m][0], 0, 0, 0);
        acc[m][1] = __builtin_amdgcn_mfma_f32_16x16x32_bf16(hv[i][m], wh[i][1], acc[m][1], 0, 0, 0);
      }

    // partial gates -> LDS
    #pragma unroll
    for (int m = 0; m < 4; ++m)
      #pragma unroll
      for (int n = 0; n < 2; ++n)
        #pragma unroll
        for (int j = 0; j < 4; ++j)
          pl[m * 16 + hi4 * 4 + j][w * 32 + n * 16 + l15] = acc[m][n][j];
    __syncthreads();

    // finish gates
    float g0 = 0.f, g1 = 0.f, g2 = 0.f, g3 = 0.f;
    #pragma unroll
    for (int ww = 0; ww < 8; ++ww) {
      g0 += pl[ob][ww * 32 +      oc];
      g1 += pl[ob][ww * 32 +  8 + oc];
      g2 += pl[ob][ww * 32 + 16 + oc];
      g3 += pl[ob][ww * 32 + 24 + oc];
    }
    float ig = sigm(g0 + bias_i);
    float fg = sigm(g1 + bias_f);
    float cg = tanh_fast(g2 + bias_g);
    float og = sigm(g3 + bias_o);
    c = fg * c + ig * cg;
    float hy = og * tanh_fast(c);

    // publish h(t+1): packed bf16 pair, agent-scope (LLC write-through)
    uint32_t mine  = (uint32_t)__builtin_bit_cast(uint16_t, (__bf16)hy);
    uint32_t other = (uint32_t)__shfl_xor((int)mine, 1);
    if (!(tid & 1))
      __hip_atomic_store(hn + ((ob * H_ + ocol) >> 1), mine | (other << 16),
                         __ATOMIC_RELAXED, __HIP_MEMORY_SCOPE_AGENT);

    if (t == T_ - 1) {
      p.out[((size_t)ob * T_ + t) * H_ + ocol] = hy;
      p.hN[ob * H_ + ocol] = hy;
      p.cN[ob * H_ + ocol] = c;
    } else {
      // drain h stores, then arrive (plain per-WG flag store, no RMW)
      asm volatile("s_waitcnt vmcnt(0)" ::: "memory");
      __syncthreads();
      if (tid == 0)
        __hip_atomic_store(p.flags + wg * 16, (uint32_t)(t + 1),
                           __ATOMIC_RELAXED, __HIP_MEMORY_SCOPE_AGENT);
      // early-issue poll load (checked after the window)
      uint32_t pv = 0xFFFFFFFFu;
      if (tid < NWG)
        pv = __hip_atomic_load(p.flags + tid * 16, __ATOMIC_RELAXED, __HIP_MEMORY_SCOPE_AGENT);

      // ---- overlap window: everything x-related + out store ----
      __builtin_nontemporal_store(hy, &p.out[((size_t)ob * T_ + t) * H_ + ocol]);

      #pragma unroll
      for (int m = 0; m < 4; ++m) { acc[m][0] = (f32x4){0,0,0,0}; acc[m][1] = (f32x4){0,0,0,0}; }
      #pragma unroll
      for (int i = 0; i < 2; ++i)
        #pragma unroll
        for (int m = 0; m < 4; ++m) {
          bf16x8 a = *(const bf16x8*)&xs[2 * w + i][m][lane][0];   // x(t+1)
          acc[m][0] = __builtin_amdgcn_mfma_f32_16x16x32_bf16(a, wx[i][0], acc[m][0], 0, 0, 0);
          acc[m][1] = __builtin_amdgcn_mfma_f32_16x16x32_bf16(a, wx[i][1], acc[m][1], 0, 0, 0);
        }

      const bool pf = (t + 2 < T_);
      float4 xf[16];
      if (pf) {
        #pragma unroll
        for (int j = 0; j < 16; ++j)
          xf[j] = *(const float4*)(p.x + ((size_t)sb * T_ + (t + 2)) * I_ + 4 * (8 * j + sr));
      }
      __syncthreads();          // xs(t+1) reads done
      if (pf) {
        #pragma unroll
        for (int j = 0; j < 16; ++j)
          *(uint2*)&xs[j][s_m][s_lf][s_off] = pack4(xf[j]);         // xs = x(t+2)
      }

      // ---- barrier check ----
      if (tid < NWG) {
        while (pv < (uint32_t)(t + 1)) {
          __builtin_amdgcn_s_sleep(1);
          pv = __hip_atomic_load(p.flags + tid * 16, __ATOMIC_RELAXED, __HIP_MEMORY_SCOPE_AGENT);
        }
      }
      __syncthreads();
    }
  }
}

extern "C" void kernel_launch(void* const* d_in, const int* in_sizes, int n_in,
                              void* d_out, int out_size, void* d_ws, size_t ws_size,
                              hipStream_t stream) {
  (void)in_sizes; (void)n_in; (void)out_size; (void)ws_size;

  P p;
  p.x     = (const float*)d_in[0];
  p.h0    = (const float*)d_in[1];
  p.c0    = (const float*)d_in[2];
  p.topic = (const float*)d_in[3];
  p.Wi    = (const float*)d_in[4];
  p.bi    = (const float*)d_in[5];
  p.Wh    = (const float*)d_in[6];
  p.bh    = (const float*)d_in[7];
  p.Wt    = (const float*)d_in[8];
  p.bt    = (const float*)d_in[9];

  float* out = (float*)d_out;
  p.out = out;
  p.hN  = out + (size_t)B_ * T_ * H_;
  p.cN  = p.hN + (size_t)B_ * H_;

  p.hb0   = (uint32_t*)d_ws;                         // 131072 B
  p.hb1   = p.hb0 + (B_ * H_ / 2);                   // 131072 B
  p.flags = (uint32_t*)((char*)d_ws + 2 * 131072);   // 128 slots, 64B apart

  lstm_init<<<dim3(128), dim3(256), 0, stream>>>(p);
  lstm_persist<<<dim3(NWG), dim3(NTHR), 0, stream>>>(p);
}

// Round 5
// 10756.798 us; speedup vs baseline: 1.1846x; 1.1846x over previous
//
#include <hip/hip_runtime.h>
#include <hip/hip_bf16.h>
#include <stdint.h>

#define B_   64
#define T_   1024
#define I_   512
#define H_   1024
#define TOP_ 256
#define NWG  128
#define NTHR 512
#define PLS  260
#define HBYTES 131072   // one h instance: 64*1024*2B

typedef __bf16 bf16x8 __attribute__((ext_vector_type(8)));
typedef float  f32x4  __attribute__((ext_vector_type(4)));
typedef uint32_t u32x4 __attribute__((ext_vector_type(4)));

struct P {
  const float *x, *h0, *c0, *topic, *Wi, *bi, *Wh, *bh, *Wt, *bt;
  float *out, *hN, *cN;
  uint32_t *hb0, *hb1;   // h publish buffers (IF$-coherent), 128 KB each
  uint8_t  *xcd;         // per-XCD L2 staging: 8 x 2 x 128 KB
  uint32_t *epoch;       // 8 producer-arrival counters, 64B apart
  uint32_t *done;        // 8 per-XCD relay-done counters, 64B apart
};

__device__ __forceinline__ bf16x8 cvt8(float4 f0, float4 f1) {
  bf16x8 v;
  v[0]=(__bf16)f0.x; v[1]=(__bf16)f0.y; v[2]=(__bf16)f0.z; v[3]=(__bf16)f0.w;
  v[4]=(__bf16)f1.x; v[5]=(__bf16)f1.y; v[6]=(__bf16)f1.z; v[7]=(__bf16)f1.w;
  return v;
}
__device__ __forceinline__ uint2 pack4(float4 f) {
  uint2 u;
  u.x = (uint32_t)__builtin_bit_cast(uint16_t, (__bf16)f.x)
      | ((uint32_t)__builtin_bit_cast(uint16_t, (__bf16)f.y) << 16);
  u.y = (uint32_t)__builtin_bit_cast(uint16_t, (__bf16)f.z)
      | ((uint32_t)__builtin_bit_cast(uint16_t, (__bf16)f.w) << 16);
  return u;
}
__device__ __forceinline__ float sigm(float x) { return 1.f / (1.f + __expf(-x)); }
__device__ __forceinline__ float tanh_fast(float z) {
  z = fminf(fmaxf(z, -15.f), 15.f);
  float e = __expf(2.f * z);
  return (e - 1.f) / (e + 1.f);
}
// 16B load bypassing L1 only (L2 hit allowed) — same-XCD coherent reads
__device__ __forceinline__ u32x4 ld16_sc0(const void* a) {
  u32x4 r;
  asm volatile("global_load_dwordx4 %0, %1, off sc0" : "=v"(r) : "v"(a));
  return r;
}
// 16B load bypassing L1+L2 (served by IF$) — cross-XCD coherent reads
__device__ __forceinline__ u32x4 ld16_sc01(const void* a) {
  u32x4 r;
  asm volatile("global_load_dwordx4 %0, %1, off sc0 sc1" : "=v"(r) : "v"(a));
  return r;
}

__global__ void lstm_init(P p) {
  int i = blockIdx.x * blockDim.x + threadIdx.x;
  if (i < 8) { p.epoch[i * 16] = 0; p.done[i * 16] = 0; }
  if (i < B_ * H_ / 2) {
    float2 f = ((const float2*)p.h0)[i];
    uint16_t lo = __builtin_bit_cast(uint16_t, (__bf16)f.x);
    uint16_t hi = __builtin_bit_cast(uint16_t, (__bf16)f.y);
    // agent-scope: goes to IF$, never dirty in a foreign L2
    __hip_atomic_store(p.hb0 + i, (uint32_t)lo | ((uint32_t)hi << 16),
                       __ATOMIC_RELAXED, __HIP_MEMORY_SCOPE_AGENT);
  }
}

__global__ __launch_bounds__(NTHR, 1) void lstm_persist(P p) {
  __shared__ ushort xs[16][4][64][8];      // x(t) in MFMA A-frag layout, 64 KB
  __shared__ float  pl[B_][PLS];           // K-partial gates, 66.5 KB

  const int wg   = blockIdx.x;
  const int tid  = threadIdx.x;
  const int lane = tid & 63;
  const int w    = tid >> 6;
  const int l15  = lane & 15;
  const int hi4  = lane >> 4;
  const int kg8  = hi4 * 8;
  // HW_REG_XCC_ID (id=20, offset 0, size 32): imm = 20 | (31<<11)
  const uint32_t xcc = __builtin_amdgcn_s_getreg(63508) & 7u;
  const uint32_t sl  = (uint32_t)(wg >> 3);   // relay slice 0..15 (8 KB each)

  // ---- relay prime: xcdbuf[xcc][0] <- hb0 (h(0)) ----
  {
    u32x4 v = ld16_sc01((const uint8_t*)p.hb0 + sl * 8192 + tid * 16);
    asm volatile("s_waitcnt vmcnt(0)" ::: "memory");
    __builtin_amdgcn_sched_barrier(0);
    *(u32x4*)(p.xcd + (size_t)xcc * 2 * HBYTES + sl * 8192 + tid * 16) = v;
    __syncthreads();   // drains stores; then signal
    if (tid == 0)
      __hip_atomic_fetch_add(p.done + xcc * 16, 1u, __ATOMIC_RELAXED, __HIP_MEMORY_SCOPE_AGENT);
  }

  // ---- weights in VGPRs: wave w owns x-chunks {2w,2w+1}, h-chunks {4w..4w+3} ----
  bf16x8 wx[2][2], wh[4][2];
  #pragma unroll
  for (int n = 0; n < 2; ++n) {
    const int row = n * 16 + l15;
    const int R   = (row >> 3) * H_ + wg * 8 + (row & 7);
    #pragma unroll
    for (int i = 0; i < 2; ++i) {
      const float* s = p.Wi + (size_t)R * I_ + (2 * w + i) * 32 + kg8;
      wx[i][n] = cvt8(*(const float4*)s, *(const float4*)(s + 4));
    }
    #pragma unroll
    for (int i = 0; i < 4; ++i) {
      const float* s = p.Wh + (size_t)R * H_ + (4 * w + i) * 32 + kg8;
      wh[i][n] = cvt8(*(const float4*)s, *(const float4*)(s + 4));
    }
  }

  const int ob = tid >> 3, oc = tid & 7, ocol = wg * 8 + oc;
  float tgv = p.bt[ocol];
  for (int j = 0; j < TOP_ / 4; ++j) {
    float4 tv = ((const float4*)(p.topic + (size_t)ob * TOP_))[j];
    float4 wv = ((const float4*)(p.Wt + (size_t)ocol * TOP_))[j];
    tgv += tv.x * wv.x + tv.y * wv.y + tv.z * wv.z + tv.w * wv.w;
  }
  const float bias_i = p.bi[ocol]        + p.bh[ocol]        + tgv;
  const float bias_f = p.bi[H_ + ocol]   + p.bh[H_ + ocol]   + tgv;
  const float bias_g = p.bi[2*H_ + ocol] + p.bh[2*H_ + ocol];
  const float bias_o = p.bi[3*H_ + ocol] + p.bh[3*H_ + ocol];
  float c = p.c0[ob * H_ + ocol];

  const int sb = tid >> 3, sr = tid & 7;
  const int s_m = sb >> 4, s_lf = (sr >> 1) * 16 + (sb & 15), s_off = (sr & 1) * 4;

  // ---- prologue: xs=x(0); acc=x-part(0); xs=x(1) ----
  #pragma unroll
  for (int j = 0; j < 16; ++j) {
    float4 f = *(const float4*)(p.x + (size_t)sb * T_ * I_ + 4 * (8 * j + sr));
    *(uint2*)&xs[j][s_m][s_lf][s_off] = pack4(f);
  }
  __syncthreads();

  f32x4 acc[4][2];
  #pragma unroll
  for (int m = 0; m < 4; ++m) { acc[m][0] = (f32x4){0,0,0,0}; acc[m][1] = (f32x4){0,0,0,0}; }
  #pragma unroll
  for (int i = 0; i < 2; ++i)
    #pragma unroll
    for (int m = 0; m < 4; ++m) {
      bf16x8 a = *(const bf16x8*)&xs[2 * w + i][m][lane][0];
      acc[m][0] = __builtin_amdgcn_mfma_f32_16x16x32_bf16(a, wx[i][0], acc[m][0], 0, 0, 0);
      acc[m][1] = __builtin_amdgcn_mfma_f32_16x16x32_bf16(a, wx[i][1], acc[m][1], 0, 0, 0);
    }
  {
    float4 xf[16];
    #pragma unroll
    for (int j = 0; j < 16; ++j)
      xf[j] = *(const float4*)(p.x + ((size_t)sb * T_ + 1) * I_ + 4 * (8 * j + sr));
    __syncthreads();
    #pragma unroll
    for (int j = 0; j < 16; ++j)
      *(uint2*)&xs[j][s_m][s_lf][s_off] = pack4(xf[j]);
  }

  for (int t = 0; t < T_; ++t) {
    const int cur = t & 1, nxt = (t + 1) & 1;

    // 1. consumer gate: my XCD's relay finished h(t)
    if (tid == 0) {
      while (__hip_atomic_load(p.done + xcc * 16, __ATOMIC_RELAXED, __HIP_MEMORY_SCOPE_AGENT)
             < 16u * (uint32_t)(t + 1))
        __builtin_amdgcn_s_sleep(1);
    }
    __syncthreads();

    // 2. h(t) from local-L2 staging (sc0: bypass L1, hit L2)
    const uint8_t* cb = p.xcd + (size_t)(xcc * 2 + cur) * HBYTES;
    u32x4 hq[4][4];
    #pragma unroll
    for (int i = 0; i < 4; ++i) {
      const int kh = (4 * w + i) * 32 + kg8;
      #pragma unroll
      for (int m = 0; m < 4; ++m)
        hq[i][m] = ld16_sc0(cb + (size_t)((m * 16 + l15) * H_ + kh) * 2);
    }
    asm volatile("s_waitcnt vmcnt(0)" ::: "memory");
    __builtin_amdgcn_sched_barrier(0);

    // 3. h MFMAs (acc already holds x-part(t))
    #pragma unroll
    for (int i = 0; i < 4; ++i)
      #pragma unroll
      for (int m = 0; m < 4; ++m) {
        union { u32x4 q; bf16x8 b; } z; z.q = hq[i][m];
        acc[m][0] = __builtin_amdgcn_mfma_f32_16x16x32_bf16(z.b, wh[i][0], acc[m][0], 0, 0, 0);
        acc[m][1] = __builtin_amdgcn_mfma_f32_16x16x32_bf16(z.b, wh[i][1], acc[m][1], 0, 0, 0);
      }

    // 4. partial gates -> LDS, reduce, finish
    #pragma unroll
    for (int m = 0; m < 4; ++m)
      #pragma unroll
      for (int n = 0; n < 2; ++n)
        #pragma unroll
        for (int j = 0; j < 4; ++j)
          pl[m * 16 + hi4 * 4 + j][w * 32 + n * 16 + l15] = acc[m][n][j];
    __syncthreads();

    float g0 = 0.f, g1 = 0.f, g2 = 0.f, g3 = 0.f;
    #pragma unroll
    for (int ww = 0; ww < 8; ++ww) {
      g0 += pl[ob][ww * 32 +      oc];
      g1 += pl[ob][ww * 32 +  8 + oc];
      g2 += pl[ob][ww * 32 + 16 + oc];
      g3 += pl[ob][ww * 32 + 24 + oc];
    }
    float ig = sigm(g0 + bias_i);
    float fg = sigm(g1 + bias_f);
    float cg = tanh_fast(g2 + bias_g);
    float og = sigm(g3 + bias_o);
    c = fg * c + ig * cg;
    float hy = og * tanh_fast(c);

    if (t < T_ - 1) {
      uint32_t* hbn = nxt ? p.hb1 : p.hb0;
      // 5. publish h(t+1) -> IF$ buffer
      uint32_t mine  = (uint32_t)__builtin_bit_cast(uint16_t, (__bf16)hy);
      uint32_t other = (uint32_t)__shfl_xor((int)mine, 1);
      if (!(tid & 1))
        __hip_atomic_store(hbn + ((ob * H_ + ocol) >> 1), mine | (other << 16),
                           __ATOMIC_RELAXED, __HIP_MEMORY_SCOPE_AGENT);
      asm volatile("s_waitcnt vmcnt(0)" ::: "memory");
      __syncthreads();     // all threads' publishes drained
      if (tid == 0)
        __hip_atomic_fetch_add(p.epoch + (wg & 7) * 16, 1u,
                               __ATOMIC_RELAXED, __HIP_MEMORY_SCOPE_AGENT);

      // 6. overlap window: out store + x-part(t+1) + x(t+2) prefetch
      __builtin_nontemporal_store(hy, &p.out[((size_t)ob * T_ + t) * H_ + ocol]);

      #pragma unroll
      for (int m = 0; m < 4; ++m) { acc[m][0] = (f32x4){0,0,0,0}; acc[m][1] = (f32x4){0,0,0,0}; }
      #pragma unroll
      for (int i = 0; i < 2; ++i)
        #pragma unroll
        for (int m = 0; m < 4; ++m) {
          bf16x8 a = *(const bf16x8*)&xs[2 * w + i][m][lane][0];   // x(t+1)
          acc[m][0] = __builtin_amdgcn_mfma_f32_16x16x32_bf16(a, wx[i][0], acc[m][0], 0, 0, 0);
          acc[m][1] = __builtin_amdgcn_mfma_f32_16x16x32_bf16(a, wx[i][1], acc[m][1], 0, 0, 0);
        }
      const bool pf = (t + 2 < T_);
      float4 xf[16];
      if (pf) {
        #pragma unroll
        for (int j = 0; j < 16; ++j)
          xf[j] = *(const float4*)(p.x + ((size_t)sb * T_ + (t + 2)) * I_ + 4 * (8 * j + sr));
      }
      __syncthreads();
      if (pf) {
        #pragma unroll
        for (int j = 0; j < 16; ++j)
          *(uint2*)&xs[j][s_m][s_lf][s_off] = pack4(xf[j]);
      }

      // 7. relay: wait all producers, pull my 8KB slice IF$ -> local L2
      if (tid < 8) {
        while (__hip_atomic_load(p.epoch + tid * 16, __ATOMIC_RELAXED, __HIP_MEMORY_SCOPE_AGENT)
               < 16u * (uint32_t)(t + 1))
          __builtin_amdgcn_s_sleep(1);
      }
      __syncthreads();
      u32x4 v = ld16_sc01((const uint8_t*)hbn + sl * 8192 + tid * 16);
      asm volatile("s_waitcnt vmcnt(0)" ::: "memory");
      __builtin_amdgcn_sched_barrier(0);
      *(u32x4*)(p.xcd + (size_t)(xcc * 2 + nxt) * HBYTES + sl * 8192 + tid * 16) = v;
      __syncthreads();     // relay stores drained (visible in local L2)
      if (tid == 0)
        __hip_atomic_fetch_add(p.done + xcc * 16, 1u,
                               __ATOMIC_RELAXED, __HIP_MEMORY_SCOPE_AGENT);
    } else {
      p.out[((size_t)ob * T_ + t) * H_ + ocol] = hy;
      p.hN[ob * H_ + ocol] = hy;
      p.cN[ob * H_ + ocol] = c;
    }
  }
}

extern "C" void kernel_launch(void* const* d_in, const int* in_sizes, int n_in,
                              void* d_out, int out_size, void* d_ws, size_t ws_size,
                              hipStream_t stream) {
  (void)in_sizes; (void)n_in; (void)out_size; (void)ws_size;

  P p;
  p.x     = (const float*)d_in[0];
  p.h0    = (const float*)d_in[1];
  p.c0    = (const float*)d_in[2];
  p.topic = (const float*)d_in[3];
  p.Wi    = (const float*)d_in[4];
  p.bi    = (const float*)d_in[5];
  p.Wh    = (const float*)d_in[6];
  p.bh    = (const float*)d_in[7];
  p.Wt    = (const float*)d_in[8];
  p.bt    = (const float*)d_in[9];

  float* out = (float*)d_out;
  p.out = out;
  p.hN  = out + (size_t)B_ * T_ * H_;
  p.cN  = p.hN + (size_t)B_ * H_;

  uint8_t* ws = (uint8_t*)d_ws;
  p.hb0   = (uint32_t*)(ws);                       // 128 KB
  p.hb1   = (uint32_t*)(ws + HBYTES);              // 128 KB
  p.xcd   = ws + 2 * HBYTES;                       // 8*2*128 KB = 2 MB
  p.epoch = (uint32_t*)(ws + 2 * HBYTES + 16 * HBYTES);          // 512 B
  p.done  = (uint32_t*)(ws + 2 * HBYTES + 16 * HBYTES + 512);    // 512 B

  lstm_init<<<dim3(128), dim3(256), 0, stream>>>(p);
  lstm_persist<<<dim3(NWG), dim3(NTHR), 0, stream>>>(p);
}

// Round 7
// 9869.339 us; speedup vs baseline: 1.2912x; 1.0899x over previous
//
#include <hip/hip_runtime.h>
#include <hip/hip_bf16.h>
#include <stdint.h>

#define B_   64
#define T_   1024
#define I_   512
#define H_   1024
#define TOP_ 256
#define NWG  128
#define NTHR 512
#define PLS  260
#define HBYTES 131072   // one h instance: 64*1024*2B

typedef __bf16 bf16x8 __attribute__((ext_vector_type(8)));
typedef float  f32x4  __attribute__((ext_vector_type(4)));
typedef uint32_t u32x4 __attribute__((ext_vector_type(4)));

struct P {
  const float *x, *h0, *c0, *topic, *Wi, *bi, *Wh, *bh, *Wt, *bt;
  float *out, *hN, *cN;
  uint32_t *hb0, *hb1;   // h publish buffers (IF$-coherent), 128 KB each
  uint8_t  *xcd;         // per-XCD L2 staging: 8 XCD x 2 slots x 128 KB
  uint32_t *pf;          // 128 producer flags, 64B apart (IF$)
  uint32_t *rdone;       // 128 (xcd,slice) relay flags, 64B apart (IF$)
};

__device__ __forceinline__ bf16x8 cvt8(float4 f0, float4 f1) {
  bf16x8 v;
  v[0]=(__bf16)f0.x; v[1]=(__bf16)f0.y; v[2]=(__bf16)f0.z; v[3]=(__bf16)f0.w;
  v[4]=(__bf16)f1.x; v[5]=(__bf16)f1.y; v[6]=(__bf16)f1.z; v[7]=(__bf16)f1.w;
  return v;
}
__device__ __forceinline__ float sigm(float x) { return 1.f / (1.f + __expf(-x)); }
__device__ __forceinline__ float tanh_fast(float z) {
  z = fminf(fmaxf(z, -15.f), 15.f);
  float e = __expf(2.f * z);
  return (e - 1.f) / (e + 1.f);
}
// L1-bypass (L2-hit) — same-XCD coherent
__device__ __forceinline__ u32x4 ld16_sc0(const void* a) {
  u32x4 r; asm volatile("global_load_dwordx4 %0, %1, off sc0" : "=v"(r) : "v"(a) : "memory"); return r;
}
// L1+L2-bypass (IF$) — cross-XCD coherent
__device__ __forceinline__ u32x4 ld16_sc01(const void* a) {
  u32x4 r; asm volatile("global_load_dwordx4 %0, %1, off sc0 sc1" : "=v"(r) : "v"(a) : "memory"); return r;
}
__device__ __forceinline__ uint32_t ld32_sc01(const void* a) {
  uint32_t r; asm volatile("global_load_dword %0, %1, off sc0 sc1" : "=v"(r) : "v"(a) : "memory"); return r;
}
__device__ __forceinline__ void st16_sc01(void* a, u32x4 v) {
  asm volatile("global_store_dwordx4 %0, %1, off sc0 sc1" :: "v"(a), "v"(v) : "memory");
}
#define WAITV0() asm volatile("s_waitcnt vmcnt(0)" ::: "memory")

__global__ void lstm_init(P p) {
  int i = blockIdx.x * blockDim.x + threadIdx.x;
  if (i < NWG) {
    __hip_atomic_store(p.pf + i * 16, 0u, __ATOMIC_RELAXED, __HIP_MEMORY_SCOPE_AGENT);
    __hip_atomic_store(p.rdone + i * 16, 0u, __ATOMIC_RELAXED, __HIP_MEMORY_SCOPE_AGENT);
  }
  if (i < B_ * H_ / 2) {
    float2 f = ((const float2*)p.h0)[i];
    uint16_t lo = __builtin_bit_cast(uint16_t, (__bf16)f.x);
    uint16_t hi = __builtin_bit_cast(uint16_t, (__bf16)f.y);
    __hip_atomic_store(p.hb0 + i, (uint32_t)lo | ((uint32_t)hi << 16),
                       __ATOMIC_RELAXED, __HIP_MEMORY_SCOPE_AGENT);
  }
}

__global__ __launch_bounds__(NTHR, 1) void lstm_persist(P p) {
  __shared__ float  pl[B_][PLS];                 // 66560 B
  __shared__ __align__(16) ushort hlds[B_][8];   // 1 KB: h gather for 16B publish

  const int tid  = threadIdx.x;
  const int wg   = blockIdx.x;
  const int lane = tid & 63;
  const int w    = tid >> 6;
  const int l15  = lane & 15;
  const int hi4  = lane >> 4;
  const int kg8  = hi4 * 8;
  const uint32_t xcc = __builtin_amdgcn_s_getreg(63508) & 7u;   // HW_REG_XCC_ID
  const uint32_t sl  = (uint32_t)(wg >> 3);                     // relay slice 0..15

  // ---- prime: xcd[xcc][0] <- hb0 (h(0)), flag rdone[xcc][sl]=1 ----
  {
    u32x4 v = ld16_sc01((const uint8_t*)p.hb0 + sl * 8192 + tid * 16);
    WAITV0(); __builtin_amdgcn_sched_barrier(0);
    *(u32x4*)(p.xcd + (size_t)(xcc * 2 + 0) * HBYTES + sl * 8192 + tid * 16) = v;
    __syncthreads();
    if (tid == 0)
      __hip_atomic_store(p.rdone + (xcc * 16u + sl) * 16, 1u,
                         __ATOMIC_RELAXED, __HIP_MEMORY_SCOPE_AGENT);
  }

  // ---- weights in VGPRs: wave w owns x-chunks {2w,2w+1}, h-chunks {4w..4w+3} ----
  bf16x8 wx[2][2], wh[4][2];
  #pragma unroll
  for (int n = 0; n < 2; ++n) {
    const int row = n * 16 + l15;
    const int R   = (row >> 3) * H_ + wg * 8 + (row & 7);
    #pragma unroll
    for (int i = 0; i < 2; ++i) {
      const float* s = p.Wi + (size_t)R * I_ + (2 * w + i) * 32 + kg8;
      wx[i][n] = cvt8(*(const float4*)s, *(const float4*)(s + 4));
    }
    #pragma unroll
    for (int i = 0; i < 4; ++i) {
      const float* s = p.Wh + (size_t)R * H_ + (4 * w + i) * 32 + kg8;
      wh[i][n] = cvt8(*(const float4*)s, *(const float4*)(s + 4));
    }
  }

  const int ob = tid >> 3, oc = tid & 7, ocol = wg * 8 + oc;
  float tgv = p.bt[ocol];
  for (int j = 0; j < TOP_ / 4; ++j) {
    float4 tv = ((const float4*)(p.topic + (size_t)ob * TOP_))[j];
    float4 wv = ((const float4*)(p.Wt + (size_t)ocol * TOP_))[j];
    tgv += tv.x * wv.x + tv.y * wv.y + tv.z * wv.z + tv.w * wv.w;
  }
  const float bias_i = p.bi[ocol]        + p.bh[ocol]        + tgv;
  const float bias_f = p.bi[H_ + ocol]   + p.bh[H_ + ocol]   + tgv;
  const float bias_g = p.bi[2*H_ + ocol] + p.bh[2*H_ + ocol];
  const float bias_o = p.bi[3*H_ + ocol] + p.bh[3*H_ + ocol];
  float c = p.c0[ob * H_ + ocol];

  // x(0) A-fragments into registers
  bf16x8 xr[2][4];
  #pragma unroll
  for (int i = 0; i < 2; ++i)
    #pragma unroll
    for (int m = 0; m < 4; ++m) {
      const float* s = p.x + ((size_t)(m * 16 + l15) * T_) * I_ + (2 * w + i) * 32 + kg8;
      xr[i][m] = cvt8(*(const float4*)s, *(const float4*)(s + 4));
    }

  for (int t = 0; t < T_; ++t) {
    const uint32_t want = (uint32_t)(t + 1);

    // x-part of gates (registers only; overlaps nothing else needed yet)
    f32x4 acc[4][2];
    #pragma unroll
    for (int m = 0; m < 4; ++m) { acc[m][0] = (f32x4){0,0,0,0}; acc[m][1] = (f32x4){0,0,0,0}; }
    #pragma unroll
    for (int i = 0; i < 2; ++i)
      #pragma unroll
      for (int m = 0; m < 4; ++m) {
        acc[m][0] = __builtin_amdgcn_mfma_f32_16x16x32_bf16(xr[i][m], wx[i][0], acc[m][0], 0, 0, 0);
        acc[m][1] = __builtin_amdgcn_mfma_f32_16x16x32_bf16(xr[i][m], wx[i][1], acc[m][1], 0, 0, 0);
      }

    // consumer gate: 16 parallel flag polls (IF$; replay-safe like R5's done)
    if (tid < 16) {
      const uint32_t* fl = p.rdone + (xcc * 16u + (uint32_t)tid) * 16;
      uint32_t v;
      do { v = ld32_sc01(fl); WAITV0(); } while (v < want);
    }
    __syncthreads();

    // h(t) from local-L2 staging
    const uint8_t* cb = p.xcd + (size_t)(xcc * 2 + (t & 1)) * HBYTES;
    u32x4 hq[4][4];
    #pragma unroll
    for (int i = 0; i < 4; ++i)
      #pragma unroll
      for (int m = 0; m < 4; ++m)
        hq[i][m] = ld16_sc0(cb + (size_t)((m * 16 + l15) * H_ + (4 * w + i) * 32 + kg8) * 2);
    WAITV0(); __builtin_amdgcn_sched_barrier(0);

    #pragma unroll
    for (int i = 0; i < 4; ++i)
      #pragma unroll
      for (int m = 0; m < 4; ++m) {
        union { u32x4 q; bf16x8 b; } z; z.q = hq[i][m];
        acc[m][0] = __builtin_amdgcn_mfma_f32_16x16x32_bf16(z.b, wh[i][0], acc[m][0], 0, 0, 0);
        acc[m][1] = __builtin_amdgcn_mfma_f32_16x16x32_bf16(z.b, wh[i][1], acc[m][1], 0, 0, 0);
      }

    // partial gates -> LDS, reduce, finish
    #pragma unroll
    for (int m = 0; m < 4; ++m)
      #pragma unroll
      for (int n = 0; n < 2; ++n)
        #pragma unroll
        for (int j = 0; j < 4; ++j)
          pl[m * 16 + hi4 * 4 + j][w * 32 + n * 16 + l15] = acc[m][n][j];
    __syncthreads();

    float g0 = 0.f, g1 = 0.f, g2 = 0.f, g3 = 0.f;
    #pragma unroll
    for (int ww = 0; ww < 8; ++ww) {
      g0 += pl[ob][ww * 32 +      oc];
      g1 += pl[ob][ww * 32 +  8 + oc];
      g2 += pl[ob][ww * 32 + 16 + oc];
      g3 += pl[ob][ww * 32 + 24 + oc];
    }
    float ig = sigm(g0 + bias_i);
    float fg = sigm(g1 + bias_f);
    float cg = tanh_fast(g2 + bias_g);
    float og = sigm(g3 + bias_o);
    c = fg * c + ig * cg;
    float hy = og * tanh_fast(c);

    if (t < T_ - 1) {
      hlds[ob][oc] = (ushort)__builtin_bit_cast(uint16_t, (__bf16)hy);
      __syncthreads();

      uint32_t* hbn = (t & 1) ? p.hb0 : p.hb1;   // h(t+1) buffer
      if (w == 0) {
        // publish: lane b stores 16B (batch row b, this WG's 8 cols) to IF$
        u32x4 v = *(const u32x4*)&hlds[lane][0];
        st16_sc01((uint8_t*)hbn + lane * 2048 + wg * 16, v);
        WAITV0();
        if (tid == 0)
          __hip_atomic_store(p.pf + wg * 16, want,
                             __ATOMIC_RELAXED, __HIP_MEMORY_SCOPE_AGENT);
      }

      // overlap window: out store + next-x fragment loads (fly under flag propagation)
      __builtin_nontemporal_store(hy, &p.out[((size_t)ob * T_ + t) * H_ + ocol]);
      #pragma unroll
      for (int i = 0; i < 2; ++i)
        #pragma unroll
        for (int m = 0; m < 4; ++m) {
          const float* s = p.x + ((size_t)(m * 16 + l15) * T_ + (t + 1)) * I_ + (2 * w + i) * 32 + kg8;
          xr[i][m] = cvt8(*(const float4*)s, *(const float4*)(s + 4));
        }

      // relay gate: 8 parallel polls of my slice's producers
      if (tid < 8) {
        const uint32_t* fl = p.pf + (8u * sl + (uint32_t)tid) * 16;
        uint32_t v;
        do { v = ld32_sc01(fl); WAITV0(); } while (v < want);
      }
      __syncthreads();

      // relay: copy my 8KB slice IF$ -> local L2, then flag
      u32x4 v2 = ld16_sc01((const uint8_t*)hbn + sl * 8192 + tid * 16);
      WAITV0(); __builtin_amdgcn_sched_barrier(0);
      *(u32x4*)(p.xcd + (size_t)(xcc * 2 + ((t + 1) & 1)) * HBYTES + sl * 8192 + tid * 16) = v2;
      __syncthreads();     // drains all waves' relay stores (vmcnt(0) before s_barrier)
      if (tid == 0)
        __hip_atomic_store(p.rdone + (xcc * 16u + sl) * 16, want + 1u,
                           __ATOMIC_RELAXED, __HIP_MEMORY_SCOPE_AGENT);
    } else {
      p.out[((size_t)ob * T_ + t) * H_ + ocol] = hy;
      p.hN[ob * H_ + ocol] = hy;
      p.cN[ob * H_ + ocol] = c;
    }
  }
}

extern "C" void kernel_launch(void* const* d_in, const int* in_sizes, int n_in,
                              void* d_out, int out_size, void* d_ws, size_t ws_size,
                              hipStream_t stream) {
  (void)in_sizes; (void)n_in; (void)out_size; (void)ws_size;

  P p;
  p.x     = (const float*)d_in[0];
  p.h0    = (const float*)d_in[1];
  p.c0    = (const float*)d_in[2];
  p.topic = (const float*)d_in[3];
  p.Wi    = (const float*)d_in[4];
  p.bi    = (const float*)d_in[5];
  p.Wh    = (const float*)d_in[6];
  p.bh    = (const float*)d_in[7];
  p.Wt    = (const float*)d_in[8];
  p.bt    = (const float*)d_in[9];

  float* out = (float*)d_out;
  p.out = out;
  p.hN  = out + (size_t)B_ * T_ * H_;
  p.cN  = p.hN + (size_t)B_ * H_;

  uint8_t* ws = (uint8_t*)d_ws;
  p.hb0   = (uint32_t*)(ws);                       // 128 KB
  p.hb1   = (uint32_t*)(ws + HBYTES);              // 128 KB
  p.xcd   = ws + 2 * HBYTES;                       // 8*2*128 KB = 2 MB
  p.pf    = (uint32_t*)(ws + 18 * HBYTES);         // 8 KB
  p.rdone = (uint32_t*)(ws + 18 * HBYTES + 8192);  // 8 KB

  lstm_init<<<dim3(128), dim3(256), 0, stream>>>(p);
  // 40 KB dynamic LDS: static 67.6 KB + 40 KB > 80 KB -> exactly 1 WG/CU,
  // preserving R5's verified round-robin 16-WG-per-XCD distribution.
  lstm_persist<<<dim3(NWG), dim3(NTHR), 40960, stream>>>(p);
}

// Round 12
// 3872.180 us; speedup vs baseline: 3.2909x; 2.5488x over previous
//
#include <hip/hip_runtime.h>
#include <hip/hip_bf16.h>
#include <stdint.h>

#define B_   64
#define T_   1024
#define I_   512
#define H_   1024
#define TOP_ 256
#define NWG  256
#define NTHR 512

typedef __bf16 bf16x8 __attribute__((ext_vector_type(8)));
typedef float  f32x4  __attribute__((ext_vector_type(4)));
typedef uint32_t u32x4 __attribute__((ext_vector_type(4)));

struct P {
  const float *x, *h0, *c0, *topic, *Wi, *bi, *Wh, *bh, *Wt, *bt;
  float *out, *hN, *cN;
  uint16_t *hs;       // h slots [2][8 grp][8 b][1024] bf16 — sc01/IF$ ops ONLY
  uint32_t *flags;    // [8 grp][32 cg], 64B apart — agent st / sc01 ld ONLY
  uint32_t *bar;      // prologue barrier counter (zeroed by lstm_init each launch)
};

__device__ __forceinline__ bf16x8 cvt8(float4 f0, float4 f1) {
  bf16x8 v;
  v[0]=(__bf16)f0.x; v[1]=(__bf16)f0.y; v[2]=(__bf16)f0.z; v[3]=(__bf16)f0.w;
  v[4]=(__bf16)f1.x; v[5]=(__bf16)f1.y; v[6]=(__bf16)f1.z; v[7]=(__bf16)f1.w;
  return v;
}
__device__ __forceinline__ float sigm(float x) { return 1.f / (1.f + __expf(-x)); }
__device__ __forceinline__ float tanh_fast(float z) {
  z = fminf(fmaxf(z, -15.f), 15.f);
  float e = __expf(2.f * z);
  return (e - 1.f) / (e + 1.f);
}
// IF$ coherence point (cross-XCD coherent) — the ONLY class used on hs/flags/bar
__device__ __forceinline__ u32x4 ld16_sc01(const void* a) {
  u32x4 r; asm volatile("global_load_dwordx4 %0, %1, off sc0 sc1" : "=v"(r) : "v"(a) : "memory"); return r;
}
__device__ __forceinline__ uint32_t ld32_sc01(const void* a) {
  uint32_t r; asm volatile("global_load_dword %0, %1, off sc0 sc1" : "=v"(r) : "v"(a) : "memory"); return r;
}
__device__ __forceinline__ void st16_sc01(void* a, u32x4 v) {
  asm volatile("global_store_dwordx4 %0, %1, off sc0 sc1" :: "v"(a), "v"(v) : "memory");
}
#define WAITV0() asm volatile("s_waitcnt vmcnt(0)" ::: "memory")

__global__ void lstm_init(P p) {
  if (threadIdx.x == 0)
    __hip_atomic_store(p.bar, 0u, __ATOMIC_RELAXED, __HIP_MEMORY_SCOPE_AGENT);
}

__global__ __launch_bounds__(NTHR, 2) void lstm_persist(P p) {
  __shared__ ushort wlds[8][8][64][8];              // 64 KB: weight chunk i==5
  __shared__ float  pl[8][132][8];                  // 33.8 KB: [wave][gate row][batch]
  __shared__ __align__(16) ushort hlds[8][32];      // 512 B: h gather for 16B publish

  const int tid  = threadIdx.x;
  const int wg   = blockIdx.x;
  const int lane = tid & 63;
  const int w    = tid >> 6;            // wave 0..7 (K-split owner)
  const int l15  = lane & 15;
  const int kb   = lane >> 4;           // k-block / C-row group
  const int mcl  = (l15 < 8) ? l15 : 7; // clamped batch row (8 real of M=16)
  const int grp = wg & 7;               // batch group (pure wg-arithmetic)
  const int cg  = wg >> 3;              // col group 0..31 (coverage by arithmetic)
  const int colbase = cg * 32;
  uint32_t* myflag = p.flags + (grp * 32 + cg) * 16;

  // zero own flag (agent — only class ever used on flags); replay-safe behind barrier
  if (tid == 0)
    __hip_atomic_store(myflag, 0u, __ATOMIC_RELAXED, __HIP_MEMORY_SCOPE_AGENT);

  // ---- weights: 48 K-chunks of 32; wave w owns chunks {w+8i, i=0..5}.
  //      i=0,1 x-chunks; i=2..5 h-chunks. i<5 -> VGPR, i==5 -> LDS.
  bf16x8 wreg[5][8];
  #pragma unroll
  for (int i = 0; i < 6; ++i) {
    const int kg = (w + 8 * i) * 32 + kb * 8;
    #pragma unroll
    for (int n = 0; n < 8; ++n) {
      const int r = n * 16 + l15;                       // local gate row 0..127
      const int R = (r >> 5) * H_ + colbase + (r & 31); // global gate row
      const float* s = (kg < I_) ? (p.Wi + (size_t)R * I_ + kg)
                                 : (p.Wh + (size_t)R * H_ + (kg - I_));
      bf16x8 v = cvt8(*(const float4*)s, *(const float4*)(s + 4));
      if (i < 5) wreg[i][n] = v;
      else       *(bf16x8*)&wlds[w][n][lane][0] = v;
    }
  }

  // ---- finisher state: tid<256 owns (b = tid&7, col = colbase + tid>>3) ----
  const int fb  = tid & 7;
  const int fcc = tid >> 3;             // 0..31 for tid<256
  const int col = colbase + (fcc & 31);
  const int gb  = grp * 8 + fb;
  float bias_i = 0, bias_f = 0, bias_g = 0, bias_o = 0, c = 0, hy_prev = 0;
  if (tid < 256) {
    float tg = p.bt[col];
    for (int j = 0; j < TOP_ / 4; ++j) {
      float4 tv = ((const float4*)(p.topic + (size_t)gb * TOP_))[j];
      float4 wv = ((const float4*)(p.Wt + (size_t)col * TOP_))[j];
      tg += tv.x * wv.x + tv.y * wv.y + tv.z * wv.z + tv.w * wv.w;
    }
    bias_i = p.bi[col]        + p.bh[col]        + tg;
    bias_f = p.bi[H_ + col]   + p.bh[H_ + col]   + tg;
    bias_g = p.bi[2*H_ + col] + p.bh[2*H_ + col];
    bias_o = p.bi[3*H_ + col] + p.bh[3*H_ + col];
    c = p.c0[(size_t)gb * H_ + col];
    hlds[fb][fcc] = (ushort)__builtin_bit_cast(
        uint16_t, (__bf16)p.h0[(size_t)gb * H_ + col]);
  }
  __syncthreads();

  // ---- publish h(0) -> slot 0 (sc01, full coverage: 32 lanes x 16B) ----
  if (w == 0 && lane < 32) {
    const int b = lane >> 2, off = (lane & 3) * 8;
    u32x4 v = *(const u32x4*)&hlds[b][off];
    st16_sc01(p.hs + ((size_t)(0 * 8 + grp) * 8 + b) * 1024 + colbase + off, v);
  }
  WAITV0();
  __syncthreads();   // all publishes + flag-zeros of this WG complete (vmcnt drained)

  // ---- one-time IF$ barrier, then open flags ----
  if (tid == 0) {
    __hip_atomic_fetch_add(p.bar, 1u, __ATOMIC_RELAXED, __HIP_MEMORY_SCOPE_AGENT);
    uint32_t it = 0, v;
    do { v = ld32_sc01(p.bar); WAITV0(); } while (v < NWG && ++it < (1u << 24));
    __hip_atomic_store(myflag, 1u, __ATOMIC_RELAXED, __HIP_MEMORY_SCOPE_AGENT);
  }
  __syncthreads();

  for (int t = 0; t < T_; ++t) {
    const uint32_t want = (uint32_t)(t + 1);

    // deferred out(t-1): drains under this step's poll
    if (t > 0 && tid < 256)
      __builtin_nontemporal_store(hy_prev, &p.out[((size_t)gb * T_ + (t - 1)) * H_ + col]);

    // issue x(t) loads (plain; latency hides under the gate poll)
    float4 xa[2][2];
    #pragma unroll
    for (int i = 0; i < 2; ++i) {
      const float* s = p.x + ((size_t)(grp * 8 + mcl) * T_ + t) * I_ + (w + 8 * i) * 32 + kb * 8;
      xa[i][0] = *(const float4*)s;
      xa[i][1] = *(const float4*)(s + 4);
    }

    // wave-granular gate: wave w consumes h cols from producers cg = w + 8*{0,1,2,3}
    {
      const uint32_t* fl = p.flags + (grp * 32 + (w + 8 * (lane & 3))) * 16;
      uint32_t it = 0;
      for (;;) {
        uint32_t v = ld32_sc01(fl);
        WAITV0();
        if (!__any((int)(v < want)) || ++it > (1u << 20)) break;  // bounded: fail-fast
        __builtin_amdgcn_s_sleep(1);
      }
      __builtin_amdgcn_sched_barrier(0);
    }

    // h(t) loads (IF$): 4 chunks x 16B per lane
    const uint16_t* hcur = p.hs + (size_t)(((t & 1) * 8 + grp) * 8) * 1024;
    u32x4 hz[4];
    #pragma unroll
    for (int i = 2; i < 6; ++i) {
      const void* a = hcur + (size_t)mcl * 1024 + ((w + 8 * i) * 32 - I_) + kb * 8;
      hz[i - 2] = ld16_sc01(a);
    }

    // x MFMAs (registers; overlap h-load latency)
    f32x4 acc[8];
    #pragma unroll
    for (int n = 0; n < 8; ++n) acc[n] = (f32x4){0, 0, 0, 0};
    #pragma unroll
    for (int i = 0; i < 2; ++i) {
      bf16x8 af = cvt8(xa[i][0], xa[i][1]);
      #pragma unroll
      for (int n = 0; n < 8; ++n)
        acc[n] = __builtin_amdgcn_mfma_f32_16x16x32_bf16(af, wreg[i][n], acc[n], 0, 0, 0);
    }

    WAITV0();
    __builtin_amdgcn_sched_barrier(0);

    // h MFMAs
    #pragma unroll
    for (int i = 2; i < 6; ++i) {
      union { u32x4 q; bf16x8 b; } z; z.q = hz[i - 2];
      #pragma unroll
      for (int n = 0; n < 8; ++n) {
        bf16x8 bb = (i < 5) ? wreg[i][n] : *(const bf16x8*)&wlds[w][n][lane][0];
        acc[n] = __builtin_amdgcn_mfma_f32_16x16x32_bf16(z.b, bb, acc[n], 0, 0, 0);
      }
    }

    // per-wave K-partials -> LDS (real batch rows only)
    #pragma unroll
    for (int n = 0; n < 8; ++n)
      if (kb < 2)
        *(f32x4*)&pl[w][n * 16 + l15][kb * 4] = acc[n];
    __syncthreads();   // sync1

    // reduce 8 K-partials, finish gates
    float hy = 0.f;
    if (tid < 256) {
      float g0 = 0, g1 = 0, g2 = 0, g3 = 0;
      #pragma unroll
      for (int ww = 0; ww < 8; ++ww) {
        g0 += pl[ww][ 0 + fcc][fb];
        g1 += pl[ww][32 + fcc][fb];
        g2 += pl[ww][64 + fcc][fb];
        g3 += pl[ww][96 + fcc][fb];
      }
      float ig  = sigm(g0 + bias_i);
      float fg  = sigm(g1 + bias_f);
      float cg_ = tanh_fast(g2 + bias_g);
      float og  = sigm(g3 + bias_o);
      c = fg * c + ig * cg_;
      hy = og * tanh_fast(c);
      if (t < T_ - 1) {
        hlds[fb][fcc] = (ushort)__builtin_bit_cast(uint16_t, (__bf16)hy);
      } else {
        __builtin_nontemporal_store(hy, &p.out[((size_t)gb * T_ + t) * H_ + col]);
        p.hN[(size_t)gb * H_ + col] = hy;
        p.cN[(size_t)gb * H_ + col] = c;
      }
      hy_prev = hy;
    }
    __syncthreads();   // sync2: hlds ready; pl reads done

    // publish h(t+1) -> slot (t+1)&1 (sc01) + flag (agent); others run ahead
    if (t < T_ - 1) {
      if (w == 0) {
        if (lane < 32) {
          const int b = lane >> 2, off = (lane & 3) * 8;
          u32x4 v = *(const u32x4*)&hlds[b][off];
          st16_sc01(p.hs + ((size_t)((((t + 1) & 1) * 8 + grp) * 8 + b) * 1024
                            + colbase + off), v);
        }
        WAITV0();                      // publishes committed at IF$ before flag
        if (tid == 0)
          __hip_atomic_store(myflag, want + 1u,
                             __ATOMIC_RELAXED, __HIP_MEMORY_SCOPE_AGENT);
      }
    }
  }
}

extern "C" void kernel_launch(void* const* d_in, const int* in_sizes, int n_in,
                              void* d_out, int out_size, void* d_ws, size_t ws_size,
                              hipStream_t stream) {
  (void)in_sizes; (void)n_in; (void)out_size; (void)ws_size;

  P p;
  p.x     = (const float*)d_in[0];
  p.h0    = (const float*)d_in[1];
  p.c0    = (const float*)d_in[2];
  p.topic = (const float*)d_in[3];
  p.Wi    = (const float*)d_in[4];
  p.bi    = (const float*)d_in[5];
  p.Wh    = (const float*)d_in[6];
  p.bh    = (const float*)d_in[7];
  p.Wt    = (const float*)d_in[8];
  p.bt    = (const float*)d_in[9];

  float* out = (float*)d_out;
  p.out = out;
  p.hN  = out + (size_t)B_ * T_ * H_;
  p.cN  = p.hN + (size_t)B_ * H_;

  uint8_t* ws = (uint8_t*)d_ws;
  p.hs    = (uint16_t*)(ws);                    // 2*8*8*1024*2 = 262144 B
  p.flags = (uint32_t*)(ws + 262144);           // 16384 B
  p.bar   = (uint32_t*)(ws + 262144 + 16384);   // 64 B

  lstm_init<<<dim3(1), dim3(64), 0, stream>>>(p);
  lstm_persist<<<dim3(NWG), dim3(NTHR), 0, stream>>>(p);
}